// Round 3
// baseline (318.895 us; speedup 1.0000x reference)
//
#include <hip/hip_runtime.h>
#include <hip/hip_bf16.h>
#include <stdint.h>

#define TOK   256
#define NOBJ  64
#define NDEMO 16
#define BATCH 256
#define SEQ   1105              /* 1 + 16*65 + 64 */
#define NDG   (NDEMO * BATCH)   /* 4096 demo groups */
#define NGRP  (NDG + BATCH)     /* 4352 total groups */

typedef __bf16 bf16x8 __attribute__((ext_vector_type(8)));
typedef float  f32x4  __attribute__((ext_vector_type(4)));

// f32 -> bf16 round-to-nearest-even, packed pair
static __device__ __forceinline__ unsigned pack_bf16x2(float a, float b) {
    unsigned ua = __float_as_uint(a);
    unsigned ub = __float_as_uint(b);
    unsigned ra = (ua + 0x7FFFu + ((ua >> 16) & 1u)) >> 16;
    unsigned rb = (ub + 0x7FFFu + ((ub >> 16) & 1u)) >> 16;
    return (ra & 0xFFFFu) | (rb << 16);
}

static __device__ __forceinline__ uint16_t f32_to_bf16_bits(float a) {
    unsigned ua = __float_as_uint(a);
    return (uint16_t)((ua + 0x7FFFu + ((ua >> 16) & 1u)) >> 16);
}

static __device__ __forceinline__ bf16x8 pack8(float4 lo, float4 hi) {
    union { uint4 u; bf16x8 b; } r;
    r.u.x = pack_bf16x2(lo.x, lo.y);
    r.u.y = pack_bf16x2(lo.z, lo.w);
    r.u.z = pack_bf16x2(hi.x, hi.y);
    r.u.w = pack_bf16x2(hi.z, hi.w);
    return r.b;
}

// ---------------------------------------------------------------------------
// Prologue: W_obj (f32, [k=256][t=256]) -> Wt (bf16 bits, [t=256][k=256])
// ---------------------------------------------------------------------------
__global__ void wconv_kernel(const float* __restrict__ W, uint16_t* __restrict__ Wt) {
    int n = blockIdx.x;
    int k = threadIdx.x;
    Wt[n * TOK + k] = f32_to_bf16_bits(W[k * TOK + n]);
}

// ---------------------------------------------------------------------------
// Main kernel: one block (512 thr, 8 waves) = one 64x256 output group.
// NO LDS, NO barriers: each wave owns a 32x64 tile, loads its A fragments
// f32 straight from global (128B-coalesced), converts in-register, MFMAs.
// Demo blocks also emit their action row; blocks 0..63 emit instr rows.
// ---------------------------------------------------------------------------
__global__ __launch_bounds__(512, 4) void obj_fused_kernel(
    const float* __restrict__ demo_obj,   // (16,256,64,256)
    const float* __restrict__ cur,        // (256,64,256)
    const float* __restrict__ b_obj,      // (256,)
    const __bf16* __restrict__ Wt,        // (256 tok, 256 k) bf16
    const float* __restrict__ demo_act,   // (16,256,7)
    const float* __restrict__ W_act,      // (7,256)
    const float* __restrict__ b_act,      // (256,)
    const float* __restrict__ instr,      // (256,768)
    const float* __restrict__ W_instr,    // (768,256)
    const float* __restrict__ b_instr,    // (256,)
    float* __restrict__ out)              // (256,1105,256)
{
    int g = blockIdx.x;
    int t = threadIdx.x;
    bool demo = (g < NDG);

    const float* srcA;
    int row_base;
    if (demo) {
        int d = g >> 8, b = g & 255;
        srcA = demo_obj + (size_t)g * (NOBJ * TOK);
        row_base = b * SEQ + 1 + d * (NOBJ + 1);
    } else {
        int b = g - NDG;
        srcA = cur + (size_t)b * (NOBJ * TOK);
        row_base = b * SEQ + 1 + NDEMO * (NOBJ + 1);
    }

    int wave = t >> 6, lane = t & 63;
    int l15 = lane & 15, l4 = lane >> 4;
    int wr = wave >> 2;    // 0..1 : 32-row half
    int wc = wave & 3;     // 0..3 : 64-col quarter
    int n0 = wc * 64;

    // A row pointers for this lane's two 16-row fragments
    const float* arow0 = srcA + (size_t)(wr * 32 + l15) * TOK + l4 * 8;
    const float* arow1 = arow0 + 16 * TOK;
    const __bf16* wbase = Wt + (size_t)(n0 + l15) * TOK + l4 * 8;

    f32x4 acc[2][4];
#pragma unroll
    for (int i = 0; i < 2; ++i)
#pragma unroll
        for (int j = 0; j < 4; ++j) {
            f32x4 z = {0.0f, 0.0f, 0.0f, 0.0f};
            acc[i][j] = z;
        }

    // prologue load (s = 0)
    float4 c0 = *reinterpret_cast<const float4*>(arow0);
    float4 c1 = *reinterpret_cast<const float4*>(arow0 + 4);
    float4 c2 = *reinterpret_cast<const float4*>(arow1);
    float4 c3 = *reinterpret_cast<const float4*>(arow1 + 4);

#pragma unroll 1
    for (int s = 0; s < 7; ++s) {
        // prefetch next k-step's A while computing this one
        float4 n0_ = *reinterpret_cast<const float4*>(arow0 + (s + 1) * 32);
        float4 n1_ = *reinterpret_cast<const float4*>(arow0 + (s + 1) * 32 + 4);
        float4 n2_ = *reinterpret_cast<const float4*>(arow1 + (s + 1) * 32);
        float4 n3_ = *reinterpret_cast<const float4*>(arow1 + (s + 1) * 32 + 4);

        bf16x8 a0 = pack8(c0, c1);
        bf16x8 a1 = pack8(c2, c3);
#pragma unroll
        for (int j = 0; j < 4; ++j) {
            bf16x8 bj = *reinterpret_cast<const bf16x8*>(wbase + (size_t)(j * 16) * TOK + s * 32);
            acc[0][j] = __builtin_amdgcn_mfma_f32_16x16x32_bf16(a0, bj, acc[0][j], 0, 0, 0);
            acc[1][j] = __builtin_amdgcn_mfma_f32_16x16x32_bf16(a1, bj, acc[1][j], 0, 0, 0);
        }
        c0 = n0_; c1 = n1_; c2 = n2_; c3 = n3_;
    }
    {   // last k-step (s = 7)
        bf16x8 a0 = pack8(c0, c1);
        bf16x8 a1 = pack8(c2, c3);
#pragma unroll
        for (int j = 0; j < 4; ++j) {
            bf16x8 bj = *reinterpret_cast<const bf16x8*>(wbase + (size_t)(j * 16) * TOK + 7 * 32);
            acc[0][j] = __builtin_amdgcn_mfma_f32_16x16x32_bf16(a0, bj, acc[0][j], 0, 0, 0);
            acc[1][j] = __builtin_amdgcn_mfma_f32_16x16x32_bf16(a1, bj, acc[1][j], 0, 0, 0);
        }
    }

    // ---- epilogue: bias + store ----
    float bv[4];
#pragma unroll
    for (int j = 0; j < 4; ++j) bv[j] = b_obj[n0 + j * 16 + l15];

#pragma unroll
    for (int i = 0; i < 2; ++i)
#pragma unroll
        for (int j = 0; j < 4; ++j) {
            int col = n0 + j * 16 + l15;
#pragma unroll
            for (int r = 0; r < 4; ++r) {
                int row = row_base + wr * 32 + i * 16 + l4 * 4 + r;
                out[(size_t)row * TOK + col] = acc[i][j][r] + bv[j];
            }
        }

    // ---- fused action row (demo groups only; waves 0..3) ----
    if (demo && t < TOK) {
        int d = g >> 8, b = g & 255;
        const float* a = demo_act + (size_t)g * 7;
        float v = b_act[t];
#pragma unroll
        for (int k = 0; k < 7; ++k) v += a[k] * W_act[k * TOK + t];
        out[(size_t)(b * SEQ + (d + 1) * (NOBJ + 1)) * TOK + t] = v;
    }

    // ---- fused instr rows: blocks 0..63 produce 4 rows each of (B,0,:) ----
    if (g < 64) {
        int b0 = g * 4;
        int col  = t & 255;
        int rsel = t >> 8;                  // 0..1 (wave-uniform)
        int r0 = b0 + rsel, r1 = b0 + rsel + 2;
        const float* i0 = instr + (size_t)r0 * 768;
        const float* i1 = instr + (size_t)r1 * 768;
        float a0 = b_instr[col], a1 = a0;
#pragma unroll 4
        for (int k = 0; k < 768; ++k) {
            float wv = W_instr[(size_t)k * TOK + col];
            a0 += i0[k] * wv;
            a1 += i1[k] * wv;
        }
        out[(size_t)r0 * SEQ * TOK + col] = a0;
        out[(size_t)r1 * SEQ * TOK + col] = a1;
    }
}

extern "C" void kernel_launch(void* const* d_in, const int* in_sizes, int n_in,
                              void* d_out, int out_size, void* d_ws, size_t ws_size,
                              hipStream_t stream) {
    (void)in_sizes; (void)n_in; (void)out_size; (void)ws_size;
    const float* instr    = (const float*)d_in[0];
    const float* demo_obj = (const float*)d_in[1];
    const float* demo_act = (const float*)d_in[2];
    const float* cur      = (const float*)d_in[3];
    const float* W_instr  = (const float*)d_in[4];
    const float* b_instr  = (const float*)d_in[5];
    const float* W_act    = (const float*)d_in[6];
    const float* b_act    = (const float*)d_in[7];
    const float* W_obj    = (const float*)d_in[8];
    const float* b_obj    = (const float*)d_in[9];
    float* out = (float*)d_out;

    uint16_t* Wt = (uint16_t*)d_ws;   // 256*256 bf16 = 128 KB

    wconv_kernel<<<256, 256, 0, stream>>>(W_obj, Wt);
    obj_fused_kernel<<<NGRP, 512, 0, stream>>>(
        demo_obj, cur, b_obj, (const __bf16*)d_ws,
        demo_act, W_act, b_act, instr, W_instr, b_instr, out);
}

// Round 4
// 289.525 us; speedup vs baseline: 1.1014x; 1.1014x over previous
//
#include <hip/hip_runtime.h>
#include <hip/hip_bf16.h>
#include <stdint.h>

#define TOK   256
#define NOBJ  64
#define NDEMO 16
#define BATCH 256
#define SEQ   1105              /* 1 + 16*65 + 64 */
#define NDG   (NDEMO * BATCH)   /* 4096 demo groups */
#define NGRP  (NDG + BATCH)     /* 4352 total groups */

#define OBJ_BLKS   (NGRP * 2)   /* 8704: one 32-row half-group per block */
#define ACT_BLKS   512          /* 8 action rows per block */
#define INSTR_BLKS 128          /* 2 instr rows per block */
#define TOTAL_BLKS (OBJ_BLKS + ACT_BLKS + INSTR_BLKS)

typedef __bf16 bf16x8 __attribute__((ext_vector_type(8)));
typedef float  f32x4  __attribute__((ext_vector_type(4)));

// f32 -> bf16 round-to-nearest-even, packed pair
static __device__ __forceinline__ unsigned pack_bf16x2(float a, float b) {
    unsigned ua = __float_as_uint(a);
    unsigned ub = __float_as_uint(b);
    unsigned ra = (ua + 0x7FFFu + ((ua >> 16) & 1u)) >> 16;
    unsigned rb = (ub + 0x7FFFu + ((ub >> 16) & 1u)) >> 16;
    return (ra & 0xFFFFu) | (rb << 16);
}

static __device__ __forceinline__ uint16_t f32_to_bf16_bits(float a) {
    unsigned ua = __float_as_uint(a);
    return (uint16_t)((ua + 0x7FFFu + ((ua >> 16) & 1u)) >> 16);
}

// ---------------------------------------------------------------------------
// Prologue: W_obj (f32, [k=256][t=256]) -> Wt (bf16 bits, [t=256][k=256])
// ---------------------------------------------------------------------------
__global__ void wconv_kernel(const float* __restrict__ W, uint16_t* __restrict__ Wt) {
    int n = blockIdx.x;
    int k = threadIdx.x;
    Wt[n * TOK + k] = f32_to_bf16_bits(W[k * TOK + n]);
}

// ---------------------------------------------------------------------------
// Single fused kernel, role-dispatched by blockIdx:
//   [0, 8704)        : obj GEMM, one 32-row half-group per block (16 KB LDS)
//   [8704, 9216)     : action rows, 8 per block
//   [9216, 9344)     : instr rows, 2 per block
// ---------------------------------------------------------------------------
__global__ __launch_bounds__(256, 6) void fused_kernel(
    const float* __restrict__ demo_obj,   // (16,256,64,256)
    const float* __restrict__ cur,        // (256,64,256)
    const float* __restrict__ b_obj,      // (256,)
    const __bf16* __restrict__ Wt,        // (256 tok, 256 k) bf16
    const float* __restrict__ demo_act,   // (16,256,7)
    const float* __restrict__ W_act,      // (7,256)
    const float* __restrict__ b_act,      // (256,)
    const float* __restrict__ instr,      // (256,768)
    const float* __restrict__ W_instr,    // (768,256)
    const float* __restrict__ b_instr,    // (256,)
    float* __restrict__ out)              // (256,1105,256)
{
    __shared__ __align__(16) unsigned char lds[16384];
    int blk = blockIdx.x;
    int t = threadIdx.x;

    if (blk < OBJ_BLKS) {
        int g = blk >> 1, half = blk & 1;
        bool demo = (g < NDG);
        const float* srcA;
        int row_base;
        if (demo) {
            int d = g >> 8, b = g & 255;
            srcA = demo_obj + (size_t)g * (NOBJ * TOK);
            row_base = b * SEQ + 1 + d * (NOBJ + 1);
        } else {
            int b = g - NDG;
            srcA = cur + (size_t)b * (NOBJ * TOK);
            row_base = b * SEQ + 1 + NDEMO * (NOBJ + 1);
        }
        srcA += half * 32 * TOK;
        row_base += half * 32;

        // ---- stage 32 rows x 256 f32 -> bf16 LDS, XOR-swizzled 16B chunks ----
#pragma unroll
        for (int c = 0; c < 4; ++c) {
            int chunk = c * 256 + t;        // 1024 chunks of 16B (bf16)
            int row = chunk >> 5;           // 32 chunks per 512B row
            int kc  = chunk & 31;
            const float4* p = reinterpret_cast<const float4*>(srcA + (size_t)chunk * 8);
            float4 v0 = p[0];
            float4 v1 = p[1];
            uint4 w;
            w.x = pack_bf16x2(v0.x, v0.y);
            w.y = pack_bf16x2(v0.z, v0.w);
            w.z = pack_bf16x2(v1.x, v1.y);
            w.w = pack_bf16x2(v1.z, v1.w);
            unsigned off = (unsigned)(row * 512 + kc * 16) ^ (unsigned)((row & 7) << 4);
            *reinterpret_cast<uint4*>(lds + off) = w;
        }
        __syncthreads();

        int wave = t >> 6, lane = t & 63;
        int l15 = lane & 15, l4 = lane >> 4;
        int n0 = wave * 64;    // this wave's 64 output columns

        f32x4 acc[2][4];
#pragma unroll
        for (int i = 0; i < 2; ++i)
#pragma unroll
            for (int j = 0; j < 4; ++j) {
                f32x4 z = {0.0f, 0.0f, 0.0f, 0.0f};
                acc[i][j] = z;
            }

#pragma unroll
        for (int s = 0; s < 8; ++s) {
            bf16x8 a[2];
#pragma unroll
            for (int i = 0; i < 2; ++i) {
                int row = i * 16 + l15;
                unsigned off = (unsigned)(row * 512 + (s * 4 + l4) * 16) ^ (unsigned)((row & 7) << 4);
                a[i] = *reinterpret_cast<const bf16x8*>(lds + off);
            }
#pragma unroll
            for (int j = 0; j < 4; ++j) {
                bf16x8 bj = *reinterpret_cast<const bf16x8*>(
                    Wt + (size_t)(n0 + j * 16 + l15) * TOK + s * 32 + l4 * 8);
                acc[0][j] = __builtin_amdgcn_mfma_f32_16x16x32_bf16(a[0], bj, acc[0][j], 0, 0, 0);
                acc[1][j] = __builtin_amdgcn_mfma_f32_16x16x32_bf16(a[1], bj, acc[1][j], 0, 0, 0);
            }
        }

        // ---- epilogue: bias + store ----
        float bv[4];
#pragma unroll
        for (int j = 0; j < 4; ++j) bv[j] = b_obj[n0 + j * 16 + l15];

#pragma unroll
        for (int i = 0; i < 2; ++i)
#pragma unroll
            for (int j = 0; j < 4; ++j) {
                int col = n0 + j * 16 + l15;
#pragma unroll
                for (int r = 0; r < 4; ++r) {
                    int row = row_base + i * 16 + l4 * 4 + r;
                    out[(size_t)row * TOK + col] = acc[i][j][r] + bv[j];
                }
            }

    } else if (blk < OBJ_BLKS + ACT_BLKS) {
        // ---- action rows: 8 consecutive groups per block ----
        int g8 = (blk - OBJ_BLKS) * 8;
        float v[8];
        float bb = b_act[t];
#pragma unroll
        for (int r = 0; r < 8; ++r) v[r] = bb;
#pragma unroll
        for (int k = 0; k < 7; ++k) {
            float wv = W_act[k * TOK + t];
#pragma unroll
            for (int r = 0; r < 8; ++r)
                v[r] += demo_act[(size_t)(g8 + r) * 7 + k] * wv;
        }
#pragma unroll
        for (int r = 0; r < 8; ++r) {
            int g = g8 + r;
            int d = g >> 8, b = g & 255;
            out[(size_t)(b * SEQ + (d + 1) * (NOBJ + 1)) * TOK + t] = v[r];
        }

    } else {
        // ---- instr rows: 2 rows per block, K=768 ----
        int b0 = (blk - OBJ_BLKS - ACT_BLKS) * 2;
        float* buf = reinterpret_cast<float*>(lds);   // 2 x 768 f32 = 6 KB
        const float* src = instr + (size_t)b0 * 768;
#pragma unroll
        for (int i = 0; i < 6; ++i) buf[i * 256 + t] = src[i * 256 + t];
        __syncthreads();
        float a0 = b_instr[t], a1 = a0;
#pragma unroll 4
        for (int k = 0; k < 768; ++k) {
            float wv = W_instr[(size_t)k * TOK + t];
            a0 += buf[k] * wv;
            a1 += buf[768 + k] * wv;
        }
        out[(size_t)b0 * SEQ * TOK + t] = a0;
        out[(size_t)(b0 + 1) * SEQ * TOK + t] = a1;
    }
}

extern "C" void kernel_launch(void* const* d_in, const int* in_sizes, int n_in,
                              void* d_out, int out_size, void* d_ws, size_t ws_size,
                              hipStream_t stream) {
    (void)in_sizes; (void)n_in; (void)out_size; (void)ws_size;
    const float* instr    = (const float*)d_in[0];
    const float* demo_obj = (const float*)d_in[1];
    const float* demo_act = (const float*)d_in[2];
    const float* cur      = (const float*)d_in[3];
    const float* W_instr  = (const float*)d_in[4];
    const float* b_instr  = (const float*)d_in[5];
    const float* W_act    = (const float*)d_in[6];
    const float* b_act    = (const float*)d_in[7];
    const float* W_obj    = (const float*)d_in[8];
    const float* b_obj    = (const float*)d_in[9];
    float* out = (float*)d_out;

    uint16_t* Wt = (uint16_t*)d_ws;   // 256*256 bf16 = 128 KB

    wconv_kernel<<<256, 256, 0, stream>>>(W_obj, Wt);
    fused_kernel<<<TOTAL_BLKS, 256, 0, stream>>>(
        demo_obj, cur, b_obj, (const __bf16*)d_ws,
        demo_act, W_act, b_act, instr, W_instr, b_instr, out);
}

// Round 5
// 152.144 us; speedup vs baseline: 2.0960x; 1.9030x over previous
//
#include <hip/hip_runtime.h>
#include <hip/hip_bf16.h>
#include <stdint.h>

#define TOK   256
#define NOBJ  64
#define NDEMO 16
#define BATCH 256
#define SEQ   1105              /* 1 + 16*65 + 64 */
#define NDG   (NDEMO * BATCH)   /* 4096 demo groups */
#define NGRP  (NDG + BATCH)     /* 4352 total groups */
#define NHT   (NGRP * 2)        /* 8704 half-tiles (32 rows each) */
#define NG    4                 /* half-tiles per obj block */
#define OBJ_BLKS   (NHT / NG)   /* 2176 */
#define ACT_BLKS   512
#define INSTR_BLKS 128
#define TOTAL_BLKS (ACT_BLKS + INSTR_BLKS + OBJ_BLKS)

typedef __bf16 bf16x8 __attribute__((ext_vector_type(8)));
typedef float  f32x4  __attribute__((ext_vector_type(4)));

static __device__ __forceinline__ unsigned pack_bf16x2(float a, float b) {
    unsigned ua = __float_as_uint(a);
    unsigned ub = __float_as_uint(b);
    unsigned ra = (ua + 0x7FFFu + ((ua >> 16) & 1u)) >> 16;
    unsigned rb = (ub + 0x7FFFu + ((ub >> 16) & 1u)) >> 16;
    return (ra & 0xFFFFu) | (rb << 16);
}

static __device__ __forceinline__ uint16_t f32_to_bf16_bits(float a) {
    unsigned ua = __float_as_uint(a);
    return (uint16_t)((ua + 0x7FFFu + ((ua >> 16) & 1u)) >> 16);
}

static __device__ __forceinline__ bf16x8 pack8(float4 lo, float4 hi) {
    union { uint4 u; bf16x8 b; } r;
    r.u.x = pack_bf16x2(lo.x, lo.y);
    r.u.y = pack_bf16x2(lo.z, lo.w);
    r.u.z = pack_bf16x2(hi.x, hi.y);
    r.u.w = pack_bf16x2(hi.z, hi.w);
    return r.b;
}

// direct global->LDS, 16B per lane (dest must be linear: base+lane*16)
static __device__ __forceinline__ void gload_lds16(const float* g, void* l) {
    __builtin_amdgcn_global_load_lds(
        (const __attribute__((address_space(1))) uint32_t*)g,
        (__attribute__((address_space(3))) uint32_t*)l,
        16, 0, 0);
}

// ---------------------------------------------------------------------------
// Prologue: W_obj (f32 [k=256][t=256]) -> Wf, bf16 in MFMA *fragment order*:
// chunk q = ((wc*4 + j)*8 + s)*64 + lane  holds Wt[t = wc*64+j*16+(lane&15)]
// [k = s*32+(lane>>4)*8 .. +7], so each wave's B-preload is contiguous 1KB.
// ---------------------------------------------------------------------------
__global__ void wconv_frag_kernel(const float* __restrict__ W, uint16_t* __restrict__ Wf) {
    int q = blockIdx.x * 256 + threadIdx.x;   // 8192 chunks of 16B
    int lane = q & 63;
    int s  = (q >> 6) & 7;
    int j  = (q >> 9) & 3;
    int wc = (q >> 11) & 3;
    int tcol = wc * 64 + j * 16 + (lane & 15);
    int k0   = s * 32 + (lane >> 4) * 8;
    uint4 w;
    unsigned p[4];
#pragma unroll
    for (int h = 0; h < 4; ++h) {
        float a = W[(size_t)(k0 + 2 * h)     * TOK + tcol];
        float b = W[(size_t)(k0 + 2 * h + 1) * TOK + tcol];
        p[h] = pack_bf16x2(a, b);
    }
    w.x = p[0]; w.y = p[1]; w.z = p[2]; w.w = p[3];
    *reinterpret_cast<uint4*>(Wf + (size_t)q * 8) = w;
}

// ---------------------------------------------------------------------------
// Fused kernel. Grid roles:
//   [0, 512)        : action rows (8 per block)
//   [512, 640)      : instr rows (2 per block)
//   [640, 640+2176) : obj GEMM, NG=4 32-row half-tiles per block,
//                     double-buffered global_load_lds + counted vmcnt pipeline
// ---------------------------------------------------------------------------
__global__ __launch_bounds__(256, 2) void fused_kernel(
    const float* __restrict__ demo_obj,   // (16,256,64,256)
    const float* __restrict__ cur,        // (256,64,256)
    const float* __restrict__ b_obj,      // (256,)
    const __bf16* __restrict__ Wf,        // fragment-ordered bf16 weights
    const float* __restrict__ demo_act,   // (16,256,7)
    const float* __restrict__ W_act,      // (7,256)
    const float* __restrict__ b_act,      // (256,)
    const float* __restrict__ instr,      // (256,768)
    const float* __restrict__ W_instr,    // (768,256)
    const float* __restrict__ b_instr,    // (256,)
    float* __restrict__ out)              // (256,1105,256)
{
    __shared__ __align__(16) float lds[2 * 32 * TOK];   // 64 KB, two 32-row f32 tiles
    int blk = blockIdx.x;
    int tid = threadIdx.x;

    if (blk >= ACT_BLKS + INSTR_BLKS) {
        // ================= obj GEMM =================
        int ob = blk - (ACT_BLKS + INSTR_BLKS);
        int h0 = ob * NG;
        // all NG half-tiles of a block are on one side of the demo/cur boundary
        const float* base = (h0 < 2 * NDG)
            ? demo_obj + (size_t)h0 * (32 * TOK)
            : cur + (size_t)(h0 - 2 * NDG) * (32 * TOK);

        int wave = tid >> 6, lane = tid & 63;
        int l15 = lane & 15, l4 = lane >> 4;
        int n0 = wave * 64;

        // per-thread staging geometry (slot = i*256+tid; r = slot>>6; c' = slot&63)
        int sr = tid >> 6;          // row within 4-row stripe (equals wave)
        int sc = tid & 63;          // chunk column in LDS (linear dest)
        // stage half-tile `it` (relative to h0) into buffer `bsel`
        auto STAGE = [&](int it, int bsel) {
            const float* sb = base + (size_t)it * (32 * TOK);
            float* dst = lds + bsel * (32 * TOK);
#pragma unroll
            for (int i = 0; i < 8; ++i) {
                int r = i * 4 + sr;
                int gch = r * 64 + (sc ^ (r & 7));   // pre-swizzled global source
                gload_lds16(sb + (size_t)gch * 4, dst + (size_t)(i * 256 + tid) * 4);
            }
        };

        // prologue: first tile's loads in flight
        STAGE(0, 0);

        // B preload: 32 contiguous 1KB wave-loads, held in 128 VGPRs
        bf16x8 bf[4][8];
        {
            const __bf16* fb = Wf + ((size_t)wave * 32 * 64 + lane) * 8;
#pragma unroll
            for (int j = 0; j < 4; ++j)
#pragma unroll
                for (int s = 0; s < 8; ++s)
                    bf[j][s] = *reinterpret_cast<const bf16x8*>(fb + (size_t)(j * 8 + s) * 64 * 8);
        }

        float bv[4];
#pragma unroll
        for (int j = 0; j < 4; ++j) bv[j] = b_obj[n0 + j * 16 + l15];

#pragma unroll 1
        for (int it = 0; it < NG; ++it) {
            if (it + 1 < NG) {
                STAGE(it + 1, (it + 1) & 1);
                asm volatile("s_waitcnt vmcnt(8)" ::: "memory");  // current tile landed; next 8 in flight
            } else {
                asm volatile("s_waitcnt vmcnt(0)" ::: "memory");
            }
            __builtin_amdgcn_s_barrier();
            __builtin_amdgcn_sched_barrier(0);

            const float* buf = lds + (it & 1) * (32 * TOK);

            f32x4 acc[2][4];
#pragma unroll
            for (int i = 0; i < 2; ++i)
#pragma unroll
                for (int j = 0; j < 4; ++j) {
                    f32x4 z = {0.0f, 0.0f, 0.0f, 0.0f};
                    acc[i][j] = z;
                }

#pragma unroll
            for (int s = 0; s < 8; ++s) {
                bf16x8 a[2];
#pragma unroll
                for (int i = 0; i < 2; ++i) {
                    int r = i * 16 + l15;
                    int c0 = s * 8 + l4 * 2;
                    float4 lo = *reinterpret_cast<const float4*>(buf + r * TOK + ((c0 ^ (r & 7)) * 4));
                    float4 hi = *reinterpret_cast<const float4*>(buf + r * TOK + (((c0 + 1) ^ (r & 7)) * 4));
                    a[i] = pack8(lo, hi);
                }
#pragma unroll
                for (int j = 0; j < 4; ++j) {
                    acc[0][j] = __builtin_amdgcn_mfma_f32_16x16x32_bf16(a[0], bf[j][s], acc[0][j], 0, 0, 0);
                    acc[1][j] = __builtin_amdgcn_mfma_f32_16x16x32_bf16(a[1], bf[j][s], acc[1][j], 0, 0, 0);
                }
            }

            // epilogue: bias + store this half-tile
            int h = h0 + it;
            int g = h >> 1, half = h & 1;
            int row_base;
            if (h < 2 * NDG) {
                int d = g >> 8, b = g & 255;
                row_base = b * SEQ + 1 + d * (NOBJ + 1) + half * 32;
            } else {
                int b = g - NDG;
                row_base = b * SEQ + 1 + NDEMO * (NOBJ + 1) + half * 32;
            }
#pragma unroll
            for (int i = 0; i < 2; ++i)
#pragma unroll
                for (int j = 0; j < 4; ++j) {
                    int col = n0 + j * 16 + l15;
#pragma unroll
                    for (int r = 0; r < 4; ++r) {
                        int row = row_base + i * 16 + l4 * 4 + r;
                        out[(size_t)row * TOK + col] = acc[i][j][r] + bv[j];
                    }
                }

            __builtin_amdgcn_s_barrier();   // all waves done reading buf before it's restaged
        }

    } else if (blk < ACT_BLKS) {
        // ================= action rows: 8 consecutive groups =================
        int g8 = blk * 8;
        int t = tid;
        float v[8];
        float bb = b_act[t];
#pragma unroll
        for (int r = 0; r < 8; ++r) v[r] = bb;
#pragma unroll
        for (int k = 0; k < 7; ++k) {
            float wv = W_act[k * TOK + t];
#pragma unroll
            for (int r = 0; r < 8; ++r)
                v[r] += demo_act[(size_t)(g8 + r) * 7 + k] * wv;
        }
#pragma unroll
        for (int r = 0; r < 8; ++r) {
            int g = g8 + r;
            int d = g >> 8, b = g & 255;
            out[(size_t)(b * SEQ + (d + 1) * (NOBJ + 1)) * TOK + t] = v[r];
        }

    } else {
        // ================= instr rows: 2 per block, K=768 =================
        int b0 = (blk - ACT_BLKS) * 2;
        int t = tid;
        float* buf = lds;   // 1536 f32 = 6 KB
        const float* src = instr + (size_t)b0 * 768;
#pragma unroll
        for (int i = 0; i < 6; ++i) buf[i * 256 + t] = src[i * 256 + t];
        __syncthreads();
        float a0 = b_instr[t], a1 = a0;
#pragma unroll 4
        for (int k = 0; k < 768; ++k) {
            float wv = W_instr[(size_t)k * TOK + t];
            a0 += buf[k] * wv;
            a1 += buf[768 + k] * wv;
        }
        out[(size_t)b0 * SEQ * TOK + t] = a0;
        out[(size_t)(b0 + 1) * SEQ * TOK + t] = a1;
    }
}

extern "C" void kernel_launch(void* const* d_in, const int* in_sizes, int n_in,
                              void* d_out, int out_size, void* d_ws, size_t ws_size,
                              hipStream_t stream) {
    (void)in_sizes; (void)n_in; (void)out_size; (void)ws_size;
    const float* instr    = (const float*)d_in[0];
    const float* demo_obj = (const float*)d_in[1];
    const float* demo_act = (const float*)d_in[2];
    const float* cur      = (const float*)d_in[3];
    const float* W_instr  = (const float*)d_in[4];
    const float* b_instr  = (const float*)d_in[5];
    const float* W_act    = (const float*)d_in[6];
    const float* b_act    = (const float*)d_in[7];
    const float* W_obj    = (const float*)d_in[8];
    const float* b_obj    = (const float*)d_in[9];
    float* out = (float*)d_out;

    uint16_t* Wf = (uint16_t*)d_ws;   // 128 KB fragment-ordered bf16 weights

    wconv_frag_kernel<<<32, 256, 0, stream>>>(W_obj, Wf);
    fused_kernel<<<TOTAL_BLKS, 256, 0, stream>>>(
        demo_obj, cur, b_obj, (const __bf16*)d_ws,
        demo_act, W_act, b_act, instr, W_instr, b_instr, out);
}